// Round 1
// baseline (44102.139 us; speedup 1.0000x reference)
//
#include <hip/hip_runtime.h>
#include <stdint.h>
#include <stddef.h>

// ===================== problem constants =====================
// B=32 S=1024 C=12 E=256 H=512 V=50000 CS=128 T=50
#define NB   32
#define NS   1024
#define NC   12
#define NE   256
#define NH   512
#define NT   50
#define NWRD 32768          // B*S
#define MC   1024           // 4*E  (char gate rows)
#define RW   2048           // 4*H  (word gate rows)
#define KW   512            // 2*E

// ===================== types / helpers =====================
typedef short bf16x8 __attribute__((ext_vector_type(8)));
typedef short bf16x4 __attribute__((ext_vector_type(4)));
typedef float f32x4  __attribute__((ext_vector_type(4)));
typedef unsigned int u32x2 __attribute__((ext_vector_type(2)));

#define MFMA16(a,b,c) __builtin_amdgcn_mfma_f32_16x16x32_bf16(a, b, c, 0, 0, 0)

__device__ __forceinline__ float bf2f(short u){
  return __uint_as_float(((uint32_t)(uint16_t)u) << 16);
}
__device__ __forceinline__ short f2bf(float f){
  uint32_t u = __float_as_uint(f);
  uint32_t r = (u + 0x7FFFu + ((u >> 16) & 1u)) >> 16;  // RNE
  return (short)r;
}
__device__ __forceinline__ float sigf(float x){
  float e = __expf(-fabsf(x));
  float s = 1.0f / (1.0f + e);
  return x >= 0.0f ? s : 1.0f - s;
}
__device__ __forceinline__ float tanh_f(float x){
  float e = __expf(-2.0f * fabsf(x));
  float r = (1.0f - e) / (1.0f + e);
  return x >= 0.0f ? r : -r;
}

// ===================== prep: PEb = char_emb @ Wc_ih^T + bc (gate-interleaved) =====================
// PEb[a][4j+g] , a<128, j<256, g in {i,f,g,o}
__global__ __launch_bounds__(256) void k_prep_pe(
    const float* __restrict__ char_emb, const float* __restrict__ Wc_ih,
    const float* __restrict__ bc, float* __restrict__ PEb)
{
  __shared__ float ce[NE];
  int a = blockIdx.x, tid = threadIdx.x;
  ce[tid] = char_emb[a * NE + tid];
  __syncthreads();
  int j = tid;
  float acc[4];
  #pragma unroll
  for (int g = 0; g < 4; ++g) acc[g] = 0.0f;
  for (int k = 0; k < NE; ++k) {
    float c = ce[k];
    #pragma unroll
    for (int g = 0; g < 4; ++g)
      acc[g] += c * Wc_ih[(size_t)(g * NE + j) * NE + k];
  }
  float4 o;
  o.x = acc[0] + bc[0 * NE + j];
  o.y = acc[1] + bc[1 * NE + j];
  o.z = acc[2] + bc[2 * NE + j];
  o.w = acc[3] + bc[3 * NE + j];
  *(float4*)&PEb[(size_t)a * MC + j * 4] = o;
}

// ===================== prep: weight convert + gate-interleave =====================
// row r = 4j+g  <-  original row g*H + j
__global__ __launch_bounds__(256) void k_prep_w(
    const float* __restrict__ Wc_hh, const float* __restrict__ Ww_ih,
    const float* __restrict__ Ww_hh, const float* __restrict__ bw,
    short* __restrict__ WhhC, short* __restrict__ WihW,
    short* __restrict__ WhhW, float* __restrict__ bwI)
{
  int r = blockIdx.x;            // 0..2047
  int j = r >> 2, g = r & 3, tid = threadIdx.x;
  if (r < MC) {                  // char Whh: [1024][256]
    float v = Wc_hh[(size_t)(g * NE + j) * NE + tid];
    WhhC[(size_t)r * NE + tid] = f2bf(v);
  }
  #pragma unroll
  for (int kk = 0; kk < 2; ++kk) {
    int k = tid + kk * 256;
    WihW[(size_t)r * KW + k] = f2bf(Ww_ih[(size_t)(g * NH + j) * KW + k]);
    WhhW[(size_t)r * NH + k] = f2bf(Ww_hh[(size_t)(g * NH + j) * NH + k]);
  }
  if (tid == 0) bwI[r] = bw[g * NH + j];
}

// ===================== char step 0 (h=c=0): pure gather + cell =====================
__global__ __launch_bounds__(256) void k_char0(
    const int* __restrict__ char_idx, const float* __restrict__ PEb,
    float* __restrict__ c_state, short* __restrict__ h_out)
{
  int w = blockIdx.x, j = threadIdx.x;
  int idx = char_idx[w * NC + 0];
  float4 pe = *(const float4*)&PEb[(size_t)idx * MC + j * 4];
  float c = sigf(pe.x) * tanh_f(pe.z);          // sig(i)*tanh(g), c_prev=0
  float h = sigf(pe.w) * tanh_f(c);             // sig(o)*tanh(c)
  c_state[(size_t)w * NE + j] = c;
  h_out[(size_t)w * NE + j] = f2bf(h);
}

// ===================== generic MFMA GEMM: D[r][n] = A[r][:]·B[n][:], fused epilogue =====================
// A: [M][KDIM] bf16 (gate rows, interleaved). B: [32768][KDIM] bf16. 128x128 block tile,
// 4 waves (2x2), wave 64x64, BK=64, XOR-swizzled LDS (chunk ^= row&7).
// EPI==0: char LSTM cell (PEb gather, c RMW fp32, h out bf16)
// EPI==1: += bias, store bf16 (PW)
template<int KDIM, int EPI>
__global__ __launch_bounds__(256) void gemm_epi(
    const short* __restrict__ Amat, const short* __restrict__ Bmat,
    const float* __restrict__ PEb, const int* __restrict__ char_idx, int tstep,
    float* __restrict__ c_state, short* __restrict__ h_out,
    const float* __restrict__ bias, short* __restrict__ pw_out)
{
  __shared__ __align__(16) short As[128 * 64];
  __shared__ __align__(16) short Bs[128 * 64];
  const int tid = threadIdx.x;
  const int lane = tid & 63;
  const int wid = tid >> 6;
  const int wm = wid >> 1, wn = wid & 1;
  const int m0 = blockIdx.y * 128;
  const int n0 = blockIdx.x * 128;
  const int lo = lane & 15, hi = lane >> 4;

  f32x4 acc[4][4];
  #pragma unroll
  for (int i = 0; i < 4; ++i)
    #pragma unroll
    for (int j = 0; j < 4; ++j) acc[i][j] = (f32x4)0.0f;

  const int nk = KDIM / 64;
  for (int ki = 0; ki < nk; ++ki) {
    __syncthreads();
    #pragma unroll
    for (int it = 0; it < 4; ++it) {          // 1024 16B-chunks per tile, 4/thread
      int cid = tid + it * 256;
      int row = cid >> 3, cp = cid & 7;
      int kch = cp ^ (row & 7);
      *(bf16x8*)&As[row * 64 + cp * 8] =
          *(const bf16x8*)&Amat[(size_t)(m0 + row) * KDIM + ki * 64 + kch * 8];
      *(bf16x8*)&Bs[row * 64 + cp * 8] =
          *(const bf16x8*)&Bmat[(size_t)(n0 + row) * KDIM + ki * 64 + kch * 8];
    }
    __syncthreads();
    #pragma unroll
    for (int kc = 0; kc < 2; ++kc) {
      bf16x8 af[4], bfr[4];
      #pragma unroll
      for (int fm = 0; fm < 4; ++fm) {
        int row = wm * 64 + fm * 16 + lo;
        int ch = (kc * 4 + hi) ^ (row & 7);
        af[fm] = *(bf16x8*)&As[row * 64 + ch * 8];
      }
      #pragma unroll
      for (int fn = 0; fn < 4; ++fn) {
        int row = wn * 64 + fn * 16 + lo;
        int ch = (kc * 4 + hi) ^ (row & 7);
        bfr[fn] = *(bf16x8*)&Bs[row * 64 + ch * 8];
      }
      #pragma unroll
      for (int fm = 0; fm < 4; ++fm)
        #pragma unroll
        for (int fn = 0; fn < 4; ++fn)
          acc[fm][fn] = MFMA16(af[fm], bfr[fn], acc[fm][fn]);
    }
  }

  // epilogue: lane holds D[r0+q][w] for q=0..3, r0 = 4j (gates i,f,g,o of one j)
  #pragma unroll
  for (int fm = 0; fm < 4; ++fm) {
    int r0 = m0 + wm * 64 + fm * 16 + hi * 4;
    #pragma unroll
    for (int fn = 0; fn < 4; ++fn) {
      int w = n0 + wn * 64 + fn * 16 + lo;
      if constexpr (EPI == 0) {
        int idx = char_idx[w * NC + tstep];
        float4 pe = *(const float4*)&PEb[(size_t)idx * MC + r0];
        float gi = acc[fm][fn][0] + pe.x;
        float gf = acc[fm][fn][1] + pe.y;
        float gg = acc[fm][fn][2] + pe.z;
        float go = acc[fm][fn][3] + pe.w;
        int j = r0 >> 2;
        float c = sigf(gf) * c_state[(size_t)w * NE + j] + sigf(gi) * tanh_f(gg);
        c_state[(size_t)w * NE + j] = c;
        h_out[(size_t)w * NE + j] = f2bf(sigf(go) * tanh_f(c));
      } else {
        float4 bb = *(const float4*)&bias[r0];
        bf16x4 o;
        o[0] = f2bf(acc[fm][fn][0] + bb.x);
        o[1] = f2bf(acc[fm][fn][1] + bb.y);
        o[2] = f2bf(acc[fm][fn][2] + bb.z);
        o[3] = f2bf(acc[fm][fn][3] + bb.w);
        *(bf16x4*)&pw_out[(size_t)w * RW + r0] = o;
      }
    }
  }
}

// ===================== build Xw = [word_emb(gather) ; char_feat] bf16, row w' = s*32+b =====================
__global__ __launch_bounds__(64) void k_xw(
    const int* __restrict__ word_idx, const float* __restrict__ word_emb,
    const short* __restrict__ h_char, short* __restrict__ Xw)
{
  int wp = blockIdx.x;             // w' = s*B + b
  int s = wp >> 5, b = wp & 31;
  int w = b * NS + s;              // char/word index order
  int tid = threadIdx.x;
  int widx = word_idx[w];
  #pragma unroll
  for (int g = 0; g < 2; ++g) {
    int k4 = (tid + g * 64) * 4;
    bf16x4 o;
    if (k4 < NE) {
      float4 v = *(const float4*)&word_emb[(size_t)widx * NE + k4];
      o[0] = f2bf(v.x); o[1] = f2bf(v.y); o[2] = f2bf(v.z); o[3] = f2bf(v.w);
    } else {
      o = *(const bf16x4*)&h_char[(size_t)w * NE + (k4 - NE)];
    }
    *(bf16x4*)&Xw[(size_t)wp * KW + k4] = o;
  }
}

// ===================== persistent word LSTM v7: single-XCD co-location =====================
// The v6 MALL-atomic exchange cost ~8250 cy/step (3.44 us), ~20x the compute. v7 elects
// ONE XCD and keeps the h all-gather inside that XCD's shared L2 (its 32 CUs' coherence
// point), dropping the store->load hop from ~900+ cy (MALL) to ~200 cy (L2 hit).
//
// Election: 256 blocks launched; each reads HW_REG_XCC_ID (s_getreg, m09-verified).
// tid0 claims slot=atomicAdd(cnt[xcc]); slot==31 CAS-publishes winner=xcc+1; everyone
// spins on winner (MALL atomics, cross-XCD correct). Winner's slots 0..31 become workers
// (bk=slot), all else exit. At 512thr x ~90 VGPR occupancy is 1 block/CU, so all 256
// blocks are co-resident -> pigeonhole: some XCD reaches 32 -> deadlock-free.
//
// Exchange protocol (same release/acquire shape as proven v6, split flag/data):
//   producer: plain u32 h-pair stores sc0 (write-through to L2) -> s_waitcnt vmcnt(0)
//             -> __syncthreads (all waves drained) -> tid0 stores flag[slot][bk]=s+1 sc0.
//   consumer: polls 2 flags (its 32-j staging slice spans 2 producer blocks) via
//             global_load_dwordx2 sc0 (L1-bypass, L2-hit); on match bulk-loads its 64B
//             h-slice once (4x dwordx4 sc0). Data is tag-free: 32KB/step broadcast,
//             poll re-reads only 8B. Slot reuse at s+2 is safe: flag(s+1) from block Q
//             implies Q's step-s data loads retired (vmcnt covers loads before flag).
//   fallback: after 256 failed sc0 polls, re-check via MALL agent atomics (false-negative
//             -only, converts any sc0-staleness surprise into slow-pass, not a hang).
__global__ __launch_bounds__(512, 2) void k_word(
    const short* __restrict__ Whh,          // [2048][512] bf16 gate-interleaved
    const short* __restrict__ PW,           // [S][B][2048] bf16 (pre-act + bias)
    uint8_t* __restrict__ xb,               // hdat[2][32][512] bf16 | flags[2][32] u32 | cnt[8]+winner
    short* __restrict__ word_hs)            // [B][S][512] bf16
{
  __shared__ __align__(16) short h_lds[2][32 * 520];   // 2 x 33280 B
  __shared__ int sh_bk;
  const int tid = threadIdx.x, lane = tid & 63, wv = tid >> 6;
  const int lo = lane & 15, hi = lane >> 4;

  // ---- XCD election ----
  uint32_t xcc;
  asm volatile("s_getreg_b32 %0, hwreg(HW_REG_XCC_ID)" : "=s"(xcc));
  xcc &= 7u;
  if (tid == 0) {
    uint32_t* cnt = (uint32_t*)(xb + 64 * 1024 + 256);
    uint32_t* win = cnt + 8;
    uint32_t slot = __hip_atomic_fetch_add(&cnt[xcc], 1u, __ATOMIC_RELAXED,
                                           __HIP_MEMORY_SCOPE_AGENT);
    if (slot == 31u) {
      uint32_t exp = 0u;
      __hip_atomic_compare_exchange_strong(win, &exp, xcc + 1u, __ATOMIC_RELAXED,
                                           __ATOMIC_RELAXED, __HIP_MEMORY_SCOPE_AGENT);
    }
    uint32_t w;
    for (;;) {
      w = __hip_atomic_load(win, __ATOMIC_RELAXED, __HIP_MEMORY_SCOPE_AGENT);
      if (w != 0u) break;
      __builtin_amdgcn_s_sleep(8);
    }
    sh_bk = (w == xcc + 1u && slot < 32u) ? (int)slot : -1;
  }
  __syncthreads();
  const int bk = sh_bk;
  if (bk < 0) return;

  const int wr = wv >> 1, wc = wv & 1;
  const int rowbase = bk * 64 + wr * 16;   // 16 gate rows for this wave
  const int b = wc * 16 + lo;              // batch column
  const int jl = (rowbase >> 2) + hi;      // this lane's j
  const int r4 = rowbase + hi * 4;         // gate-group base row

  // resident weights: rows rowbase..rowbase+15, full K=512 (16 frags = 64 VGPR)
  bf16x8 a[16];
  #pragma unroll
  for (int kc = 0; kc < 16; ++kc)
    a[kc] = *(const bf16x8*)&Whh[(size_t)(rowbase + lo) * NH + kc * 32 + hi * 8];

  short*    hdat  = (short*)xb;                       // [2][32][512] bf16
  uint32_t* flags = (uint32_t*)(xb + 64 * 1024);      // [2][32]

  const int sb = tid >> 4, sj = (tid & 15) * 32;      // staging slice: h[sb][sj..sj+32)
  const int bk2 = (tid & 15) * 2;                     // producer flag pair covering sj

  float cst = 0.0f;
  bf16x4 pw = *(const bf16x4*)&PW[(size_t)(0 * NB + b) * RW + r4];

  for (int s = 0; s < NS; ++s) {
    const uint32_t tv = (uint32_t)s;

    // ---- poll the 2 producer flags for this thread's staging slice (L2-hit sc0) ----
    {
      const uint32_t* fp = flags + ((s & 1) << 5) + bk2;
      int tries = 0;
      for (;;) {
        u32x2 fv;
        asm volatile("global_load_dwordx2 %0, %1, off sc0\n\t"
                     "s_waitcnt vmcnt(0)"
                     : "=v"(fv) : "v"(fp));
        if (fv[0] == tv && fv[1] == tv) break;
        if (++tries > 256) {   // safety net: MALL-coherent re-check
          uint32_t f0 = __hip_atomic_load(&fp[0], __ATOMIC_RELAXED, __HIP_MEMORY_SCOPE_AGENT);
          uint32_t f1 = __hip_atomic_load(&fp[1], __ATOMIC_RELAXED, __HIP_MEMORY_SCOPE_AGENT);
          if (f0 == tv && f1 == tv) break;
          tries = 0;
        }
        __builtin_amdgcn_s_sleep(1);
      }
    }

    // ---- bulk-load this thread's 64B h-slice (valid now), L1-bypassed ----
    const short* sp = hdat + ((s & 1) << 14) + sb * 512 + sj;
    bf16x8 d0, d1, d2, d3;
    asm volatile("global_load_dwordx4 %0, %4, off sc0\n\t"
                 "global_load_dwordx4 %1, %4, off offset:16 sc0\n\t"
                 "global_load_dwordx4 %2, %4, off offset:32 sc0\n\t"
                 "global_load_dwordx4 %3, %4, off offset:48 sc0\n\t"
                 "s_waitcnt vmcnt(0)"
                 : "=v"(d0), "=v"(d1), "=v"(d2), "=v"(d3) : "v"(sp));

    // prefetch next-step PW: in flight across LDS stage + MFMA + cell (~600+cy of cover
    // before the producer-side vmcnt(0) force-drains it -> ~200cy residual, off poll path)
    int sn = (s + 1 < NS) ? (s + 1) : (NS - 1);
    bf16x4 pwn = *(const bf16x4*)&PW[(size_t)(sn * NB + b) * RW + r4];

    short* buf = &h_lds[s & 1][0];
    short* dst = buf + sb * 520 + sj;
    *(bf16x8*)&dst[0]  = d0;
    *(bf16x8*)&dst[8]  = d1;
    *(bf16x8*)&dst[16] = d2;
    *(bf16x8*)&dst[24] = d3;
    __syncthreads();

    // ---- gates = PW + Whh @ h : 16 MFMAs in two independent dep-chains ----
    f32x4 acc, acc1;
    #pragma unroll
    for (int q = 0; q < 4; ++q) { acc[q] = bf2f(pw[q]); acc1[q] = 0.0f; }
    #pragma unroll
    for (int kc = 0; kc < 16; kc += 2) {
      bf16x8 hb0 = *(bf16x8*)((const char*)buf + b * 1040 + kc * 64 + hi * 16);
      bf16x8 hb1 = *(bf16x8*)((const char*)buf + b * 1040 + (kc + 1) * 64 + hi * 16);
      acc  = MFMA16(a[kc],     hb0, acc);
      acc1 = MFMA16(a[kc + 1], hb1, acc1);
    }
    #pragma unroll
    for (int q = 0; q < 4; ++q) acc[q] += acc1[q];

    // ---- cell (1 j per lane) ----
    float c = sigf(acc[1]) * cst + sigf(acc[0]) * tanh_f(acc[2]);
    cst = c;
    short hv = f2bf(sigf(acc[3]) * tanh_f(c));
    word_hs[((size_t)b * NS + s) * NH + jl] = hv;

    // ---- publish h(s+1): pair-pack via shfl_xor(16), plain u32 store -> this XCD's L2 ----
    unsigned int own = (unsigned int)(unsigned short)hv;
    unsigned int part = (unsigned int)__shfl_xor((int)own, 16);
    if ((hi & 1) == 0) {
      unsigned int val = own | (part << 16);          // mem: [jl]=own, [jl+1]=part
      short* hp = hdat + (((s + 1) & 1) << 14) + b * 512 + jl;
      asm volatile("global_store_dword %0, %1, off sc0" :: "v"(hp), "v"(val) : "memory");
    }
    asm volatile("s_waitcnt vmcnt(0)" ::: "memory");  // h stores ack'd by L2
    __syncthreads();                                  // all waves of block drained
    if (tid == 0) {
      uint32_t* fq = flags + (((s + 1) & 1) << 5) + bk;
      asm volatile("global_store_dword %0, %1, off sc0"
                   :: "v"(fq), "v"((uint32_t)(s + 1)) : "memory");
    }
    pw = pwn;
  }
}

// ===================== tag projection + log_softmax =====================
// M=64 tags (padded), N=128 words/block, K=512. Wt staged bf16 in LDS (two K-halves).
__global__ __launch_bounds__(256) void k_tags(
    const short* __restrict__ word_hs, const float* __restrict__ Wt,
    const float* __restrict__ bt, float* __restrict__ out)
{
  __shared__ __align__(16) short Ws[64 * 256];   // 32KB: one K-half
  const int tid = threadIdx.x, lane = tid & 63, wid = tid >> 6;
  const int lo = lane & 15, hi = lane >> 4;
  const int n0 = blockIdx.x * 128;
  const int wb = n0 + wid * 32;

  f32x4 acc[4][2];
  #pragma unroll
  for (int fm = 0; fm < 4; ++fm)
    #pragma unroll
    for (int fn = 0; fn < 2; ++fn) acc[fm][fn] = (f32x4)0.0f;

  for (int half = 0; half < 2; ++half) {
    __syncthreads();
    for (int cid = tid; cid < 2048; cid += 256) {   // 64 rows x 32 chunks
      int row = cid >> 5, cp = cid & 31;
      int kch = cp ^ (row & 7);
      bf16x8 v;
      if (row < NT) {
        const float* src = &Wt[(size_t)row * KW + half * 256 + kch * 8];
        #pragma unroll
        for (int e = 0; e < 8; ++e) v[e] = f2bf(src[e]);
      } else v = (bf16x8)0;
      *(bf16x8*)&Ws[row * 256 + cp * 8] = v;
    }
    __syncthreads();
    #pragma unroll
    for (int kc = 0; kc < 8; ++kc) {
      bf16x8 bfr[2];
      #pragma unroll
      for (int fn = 0; fn < 2; ++fn) {
        int w = wb + fn * 16 + lo;
        bfr[fn] = *(const bf16x8*)&word_hs[(size_t)w * KW + half * 256 + kc * 32 + hi * 8];
      }
      #pragma unroll
      for (int fm = 0; fm < 4; ++fm) {
        int row = fm * 16 + lo;
        int ch = (kc * 4 + hi) ^ (row & 7);
        bf16x8 av = *(bf16x8*)&Ws[row * 256 + ch * 8];
        acc[fm][0] = MFMA16(av, bfr[0], acc[fm][0]);
        acc[fm][1] = MFMA16(av, bfr[1], acc[fm][1]);
      }
    }
  }

  #pragma unroll
  for (int fn = 0; fn < 2; ++fn) {
    int w = wb + fn * 16 + lo;
    float lg[16];
    float m = -1e30f;
    #pragma unroll
    for (int fm = 0; fm < 4; ++fm)
      #pragma unroll
      for (int q = 0; q < 4; ++q) {
        int tg = fm * 16 + hi * 4 + q;
        float bv = (tg < NT) ? bt[tg] : 0.0f;
        float v = acc[fm][fn][q] + bv;
        lg[fm * 4 + q] = v;
        if (tg < NT) m = fmaxf(m, v);
      }
    m = fmaxf(m, __shfl_xor(m, 16));
    m = fmaxf(m, __shfl_xor(m, 32));
    float s = 0.0f;
    #pragma unroll
    for (int fm = 0; fm < 4; ++fm)
      #pragma unroll
      for (int q = 0; q < 4; ++q) {
        int tg = fm * 16 + hi * 4 + q;
        if (tg < NT) s += __expf(lg[fm * 4 + q] - m);
      }
    s += __shfl_xor(s, 16);
    s += __shfl_xor(s, 32);
    float lz = m + __logf(s);
    #pragma unroll
    for (int fm = 0; fm < 4; ++fm)
      #pragma unroll
      for (int q = 0; q < 4; ++q) {
        int tg = fm * 16 + hi * 4 + q;
        if (tg < NT) out[(size_t)w * NT + tg] = lg[fm * 4 + q] - lz;
      }
  }
}

// ===================== launch =====================
extern "C" void kernel_launch(void* const* d_in, const int* in_sizes, int n_in,
                              void* d_out, int out_size, void* d_ws, size_t ws_size,
                              hipStream_t stream) {
  const int*   char_idx = (const int*)  d_in[0];
  const int*   word_idx = (const int*)  d_in[1];
  const float* char_emb = (const float*)d_in[2];
  const float* word_emb = (const float*)d_in[3];
  const float* Wc_ih    = (const float*)d_in[4];
  const float* Wc_hh    = (const float*)d_in[5];
  const float* bc       = (const float*)d_in[6];
  const float* Ww_ih    = (const float*)d_in[7];
  const float* Ww_hh    = (const float*)d_in[8];
  const float* bw       = (const float*)d_in[9];
  const float* Wt       = (const float*)d_in[10];
  const float* bt       = (const float*)d_in[11];
  float* out = (float*)d_out;

  const size_t MB = 1ull << 20;
  uint8_t* w8 = (uint8_t*)d_ws;
  float* PEb   = (float*)(w8 + 0);                 // 512K
  short* WhhC  = (short*)(w8 + 512 * 1024);        // 512K
  short* WihW  = (short*)(w8 + 1 * MB);            // 2M
  short* WhhW  = (short*)(w8 + 3 * MB);            // 2M
  float* bwI   = (float*)(w8 + 5 * MB);            // 8K
  uint8_t* xb  = (uint8_t*)(w8 + 5 * MB + 64 * 1024);  // 64K hdat + 256B flags + 64B elect
  short* hA    = (short*)(w8 + 6 * MB);            // 16M
  short* hB    = (short*)(w8 + 22 * MB);           // 16M
  short* whs   = (short*)(w8 + 6 * MB);            // 32M (reuses hA/hB after k_xw)
  float* cC    = (float*)(w8 + 38 * MB);           // 32M
  short* Xw    = (short*)(w8 + 38 * MB);           // 32M (reuses cC after char steps)
  short* PW    = (short*)(w8 + 70 * MB);           // 128M

  k_prep_pe<<<128, 256, 0, stream>>>(char_emb, Wc_ih, bc, PEb);
  k_prep_w<<<2048, 256, 0, stream>>>(Wc_hh, Ww_ih, Ww_hh, bw, WhhC, WihW, WhhW, bwI);

  // char LSTM
  k_char0<<<NWRD, 256, 0, stream>>>(char_idx, PEb, cC, hA);
  for (int t = 1; t < NC; ++t) {
    short* src = (t & 1) ? hA : hB;
    short* dst = (t & 1) ? hB : hA;
    gemm_epi<256, 0><<<dim3(256, 8), 256, 0, stream>>>(
        WhhC, src, PEb, char_idx, t, cC, dst, nullptr, nullptr);
  }
  // h_12 ends in hB

  // word LSTM input projections for all timesteps
  k_xw<<<NWRD, 64, 0, stream>>>(word_idx, word_emb, hB, Xw);
  gemm_epi<512, 1><<<dim3(256, 16), 256, 0, stream>>>(
      WihW, Xw, nullptr, nullptr, 0, nullptr, nullptr, bwI, PW);

  // persistent recurrence: zero h slot0 (h_{-1}=0), both flag slots, election state
  hipMemsetAsync(xb, 0, 64 * 1024 + 512, stream);
  k_word<<<256, 512, 0, stream>>>(WhhW, PW, xb, whs);

  // tags + log_softmax
  k_tags<<<256, 256, 0, stream>>>(whs, Wt, bt, out);
}

// Round 2
// 4423.122 us; speedup vs baseline: 9.9708x; 9.9708x over previous
//
#include <hip/hip_runtime.h>
#include <stdint.h>
#include <stddef.h>

// ===================== problem constants =====================
// B=32 S=1024 C=12 E=256 H=512 V=50000 CS=128 T=50
#define NB   32
#define NS   1024
#define NC   12
#define NE   256
#define NH   512
#define NT   50
#define NWRD 32768          // B*S
#define MC   1024           // 4*E  (char gate rows)
#define RW   2048           // 4*H  (word gate rows)
#define KW   512            // 2*E

// ===================== types / helpers =====================
typedef short bf16x8 __attribute__((ext_vector_type(8)));
typedef short bf16x4 __attribute__((ext_vector_type(4)));
typedef float f32x4  __attribute__((ext_vector_type(4)));
typedef unsigned int u32x4 __attribute__((ext_vector_type(4)));

#define MFMA16(a,b,c) __builtin_amdgcn_mfma_f32_16x16x32_bf16(a, b, c, 0, 0, 0)

__device__ __forceinline__ float bf2f(short u){
  return __uint_as_float(((uint32_t)(uint16_t)u) << 16);
}
__device__ __forceinline__ short f2bf(float f){
  uint32_t u = __float_as_uint(f);
  uint32_t r = (u + 0x7FFFu + ((u >> 16) & 1u)) >> 16;  // RNE
  return (short)r;
}
__device__ __forceinline__ float sigf(float x){
  float e = __expf(-fabsf(x));
  float s = 1.0f / (1.0f + e);
  return x >= 0.0f ? s : 1.0f - s;
}
__device__ __forceinline__ float tanh_f(float x){
  float e = __expf(-2.0f * fabsf(x));
  float r = (1.0f - e) / (1.0f + e);
  return x >= 0.0f ? r : -r;
}

// ===================== prep: PEb = char_emb @ Wc_ih^T + bc (gate-interleaved) =====================
// PEb[a][4j+g] , a<128, j<256, g in {i,f,g,o}
__global__ __launch_bounds__(256) void k_prep_pe(
    const float* __restrict__ char_emb, const float* __restrict__ Wc_ih,
    const float* __restrict__ bc, float* __restrict__ PEb)
{
  __shared__ float ce[NE];
  int a = blockIdx.x, tid = threadIdx.x;
  ce[tid] = char_emb[a * NE + tid];
  __syncthreads();
  int j = tid;
  float acc[4];
  #pragma unroll
  for (int g = 0; g < 4; ++g) acc[g] = 0.0f;
  for (int k = 0; k < NE; ++k) {
    float c = ce[k];
    #pragma unroll
    for (int g = 0; g < 4; ++g)
      acc[g] += c * Wc_ih[(size_t)(g * NE + j) * NE + k];
  }
  float4 o;
  o.x = acc[0] + bc[0 * NE + j];
  o.y = acc[1] + bc[1 * NE + j];
  o.z = acc[2] + bc[2 * NE + j];
  o.w = acc[3] + bc[3 * NE + j];
  *(float4*)&PEb[(size_t)a * MC + j * 4] = o;
}

// ===================== prep: weight convert + gate-interleave =====================
// row r = 4j+g  <-  original row g*H + j
__global__ __launch_bounds__(256) void k_prep_w(
    const float* __restrict__ Wc_hh, const float* __restrict__ Ww_ih,
    const float* __restrict__ Ww_hh, const float* __restrict__ bw,
    short* __restrict__ WhhC, short* __restrict__ WihW,
    short* __restrict__ WhhW, float* __restrict__ bwI)
{
  int r = blockIdx.x;            // 0..2047
  int j = r >> 2, g = r & 3, tid = threadIdx.x;
  if (r < MC) {                  // char Whh: [1024][256]
    float v = Wc_hh[(size_t)(g * NE + j) * NE + tid];
    WhhC[(size_t)r * NE + tid] = f2bf(v);
  }
  #pragma unroll
  for (int kk = 0; kk < 2; ++kk) {
    int k = tid + kk * 256;
    WihW[(size_t)r * KW + k] = f2bf(Ww_ih[(size_t)(g * NH + j) * KW + k]);
    WhhW[(size_t)r * NH + k] = f2bf(Ww_hh[(size_t)(g * NH + j) * NH + k]);
  }
  if (tid == 0) bwI[r] = bw[g * NH + j];
}

// ===================== char step 0 (h=c=0): pure gather + cell =====================
__global__ __launch_bounds__(256) void k_char0(
    const int* __restrict__ char_idx, const float* __restrict__ PEb,
    float* __restrict__ c_state, short* __restrict__ h_out)
{
  int w = blockIdx.x, j = threadIdx.x;
  int idx = char_idx[w * NC + 0];
  float4 pe = *(const float4*)&PEb[(size_t)idx * MC + j * 4];
  float c = sigf(pe.x) * tanh_f(pe.z);          // sig(i)*tanh(g), c_prev=0
  float h = sigf(pe.w) * tanh_f(c);             // sig(o)*tanh(c)
  c_state[(size_t)w * NE + j] = c;
  h_out[(size_t)w * NE + j] = f2bf(h);
}

// ===================== generic MFMA GEMM: D[r][n] = A[r][:]·B[n][:], fused epilogue =====================
// A: [M][KDIM] bf16 (gate rows, interleaved). B: [32768][KDIM] bf16. 128x128 block tile,
// 4 waves (2x2), wave 64x64, BK=64, XOR-swizzled LDS (chunk ^= row&7).
// EPI==0: char LSTM cell (PEb gather, c RMW fp32, h out bf16)
// EPI==1: += bias, store bf16 (PW)
template<int KDIM, int EPI>
__global__ __launch_bounds__(256) void gemm_epi(
    const short* __restrict__ Amat, const short* __restrict__ Bmat,
    const float* __restrict__ PEb, const int* __restrict__ char_idx, int tstep,
    float* __restrict__ c_state, short* __restrict__ h_out,
    const float* __restrict__ bias, short* __restrict__ pw_out)
{
  __shared__ __align__(16) short As[128 * 64];
  __shared__ __align__(16) short Bs[128 * 64];
  const int tid = threadIdx.x;
  const int lane = tid & 63;
  const int wid = tid >> 6;
  const int wm = wid >> 1, wn = wid & 1;
  const int m0 = blockIdx.y * 128;
  const int n0 = blockIdx.x * 128;
  const int lo = lane & 15, hi = lane >> 4;

  f32x4 acc[4][4];
  #pragma unroll
  for (int i = 0; i < 4; ++i)
    #pragma unroll
    for (int j = 0; j < 4; ++j) acc[i][j] = (f32x4)0.0f;

  const int nk = KDIM / 64;
  for (int ki = 0; ki < nk; ++ki) {
    __syncthreads();
    #pragma unroll
    for (int it = 0; it < 4; ++it) {          // 1024 16B-chunks per tile, 4/thread
      int cid = tid + it * 256;
      int row = cid >> 3, cp = cid & 7;
      int kch = cp ^ (row & 7);
      *(bf16x8*)&As[row * 64 + cp * 8] =
          *(const bf16x8*)&Amat[(size_t)(m0 + row) * KDIM + ki * 64 + kch * 8];
      *(bf16x8*)&Bs[row * 64 + cp * 8] =
          *(const bf16x8*)&Bmat[(size_t)(n0 + row) * KDIM + ki * 64 + kch * 8];
    }
    __syncthreads();
    #pragma unroll
    for (int kc = 0; kc < 2; ++kc) {
      bf16x8 af[4], bfr[4];
      #pragma unroll
      for (int fm = 0; fm < 4; ++fm) {
        int row = wm * 64 + fm * 16 + lo;
        int ch = (kc * 4 + hi) ^ (row & 7);
        af[fm] = *(bf16x8*)&As[row * 64 + ch * 8];
      }
      #pragma unroll
      for (int fn = 0; fn < 4; ++fn) {
        int row = wn * 64 + fn * 16 + lo;
        int ch = (kc * 4 + hi) ^ (row & 7);
        bfr[fn] = *(bf16x8*)&Bs[row * 64 + ch * 8];
      }
      #pragma unroll
      for (int fm = 0; fm < 4; ++fm)
        #pragma unroll
        for (int fn = 0; fn < 4; ++fn)
          acc[fm][fn] = MFMA16(af[fm], bfr[fn], acc[fm][fn]);
    }
  }

  // epilogue: lane holds D[r0+q][w] for q=0..3, r0 = 4j (gates i,f,g,o of one j)
  #pragma unroll
  for (int fm = 0; fm < 4; ++fm) {
    int r0 = m0 + wm * 64 + fm * 16 + hi * 4;
    #pragma unroll
    for (int fn = 0; fn < 4; ++fn) {
      int w = n0 + wn * 64 + fn * 16 + lo;
      if constexpr (EPI == 0) {
        int idx = char_idx[w * NC + tstep];
        float4 pe = *(const float4*)&PEb[(size_t)idx * MC + r0];
        float gi = acc[fm][fn][0] + pe.x;
        float gf = acc[fm][fn][1] + pe.y;
        float gg = acc[fm][fn][2] + pe.z;
        float go = acc[fm][fn][3] + pe.w;
        int j = r0 >> 2;
        float c = sigf(gf) * c_state[(size_t)w * NE + j] + sigf(gi) * tanh_f(gg);
        c_state[(size_t)w * NE + j] = c;
        h_out[(size_t)w * NE + j] = f2bf(sigf(go) * tanh_f(c));
      } else {
        float4 bb = *(const float4*)&bias[r0];
        bf16x4 o;
        o[0] = f2bf(acc[fm][fn][0] + bb.x);
        o[1] = f2bf(acc[fm][fn][1] + bb.y);
        o[2] = f2bf(acc[fm][fn][2] + bb.z);
        o[3] = f2bf(acc[fm][fn][3] + bb.w);
        *(bf16x4*)&pw_out[(size_t)w * RW + r0] = o;
      }
    }
  }
}

// ===================== build Xw = [word_emb(gather) ; char_feat] bf16, row w' = s*32+b =====================
__global__ __launch_bounds__(64) void k_xw(
    const int* __restrict__ word_idx, const float* __restrict__ word_emb,
    const short* __restrict__ h_char, short* __restrict__ Xw)
{
  int wp = blockIdx.x;             // w' = s*B + b
  int s = wp >> 5, b = wp & 31;
  int w = b * NS + s;              // char/word index order
  int tid = threadIdx.x;
  int widx = word_idx[w];
  #pragma unroll
  for (int g = 0; g < 2; ++g) {
    int k4 = (tid + g * 64) * 4;
    bf16x4 o;
    if (k4 < NE) {
      float4 v = *(const float4*)&word_emb[(size_t)widx * NE + k4];
      o[0] = f2bf(v.x); o[1] = f2bf(v.y); o[2] = f2bf(v.z); o[3] = f2bf(v.w);
    } else {
      o = *(const bf16x4*)&h_char[(size_t)w * NE + (k4 - NE)];
    }
    *(bf16x4*)&Xw[(size_t)wp * KW + k4] = o;
  }
}

// ===================== persistent word LSTM v8: MALL exchange, request-count-minimized =====================
// v6 (tagged-u64 agent atomics) = 3.44us/step: the poll issued 16 separate 8B MALL
// requests/thread/round (262k requests/round) -> fabric request-rate bound. v7 proved
// sc0 (SE-scope) stores sit dirty in L2, invisible at MALL for ~40us -> all exchange
// ops must be sc1 (device scope, the bits agent-scope atomics compile to).
//
// v8 protocol (all exchange accesses sc1):
//   data: dense untagged hdat[2][32][512] bf16. Consumer thread loads its 64B slice as
//         4x dwordx4, laid out so each wave instruction covers 4x256B contiguous chunks
//         (8 line-requests/instr) -- one shot, not polled.
//   flags: per-wave flags[2][256]. Producer wave: pair-stores (dword sc1) ->
//         s_waitcnt vmcnt(0) (sc1 stores ack at device coherence point; nothing is
//         L2-dirty so this IS the release fence) -> lane0 stores waveflag=s+1 sc1.
//         Consumer polls with ONE dwordx4/lane (1KB coalesced/wave/round) + ballot.
//   ordering: flag(s+1) from wave W of block Z postdates Z's in-block barrier(s),
//         which postdates ALL Z-waves' slot-((s+1)&1) reads of step s-1 -> slot
//         overwrite safe. Within block, the single barrier after LDS-stage bounds
//         wave skew to <1 step (all waves pass barrier(s) together).
//   fallback: every 768 failed rounds re-check via agent atomics (liveness net).
__global__ __launch_bounds__(512, 2) void k_word(
    const short* __restrict__ Whh,          // [2048][512] bf16 gate-interleaved
    const short* __restrict__ PW,           // [S][B][2048] bf16 (pre-act + bias)
    uint8_t* __restrict__ xb,               // hdat[2][32][512] bf16 | flags[2][256] u32
    short* __restrict__ word_hs)            // [B][S][512] bf16
{
  __shared__ __align__(16) short h_lds[2][32 * 520];   // 2 x 33280 B
  const int tid = threadIdx.x, lane = tid & 63, wv = tid >> 6;
  const int lo = lane & 15, hi = lane >> 4;
  const int bk = blockIdx.x;               // 0..31
  const int wr = wv >> 1, wc = wv & 1;
  const int rowbase = bk * 64 + wr * 16;   // 16 gate rows for this wave
  const int b = wc * 16 + lo;              // batch column
  const int jl = (rowbase >> 2) + hi;      // this lane's j
  const int r4 = rowbase + hi * 4;         // gate-group base row

  // resident weights: rows rowbase..rowbase+15, full K=512 (16 frags = 64 VGPR)
  bf16x8 a[16];
  #pragma unroll
  for (int kc = 0; kc < 16; ++kc)
    a[kc] = *(const bf16x8*)&Whh[(size_t)(rowbase + lo) * NH + kc * 32 + hi * 8];

  short*    hdat  = (short*)xb;                   // [2][32][512] bf16 (slot = 16384 shorts)
  uint32_t* flags = (uint32_t*)(xb + 65536);      // [2][256] per-wave flags

  // consumer data slice: batch db, shorts {dlo + k*128 .. +8} for k=0..3
  const int db = tid >> 4, dlo = (tid & 15) * 8;
  const short* dA = hdat + db * 512 + dlo;        // slot 0
  const short* dB = dA + 16384;                   // slot 1
  const uint32_t* fA = flags + lane * 4;          // slot 0: 4 flags per lane covers 256
  const uint32_t* fB = fA + 256;                  // slot 1

  float cst = 0.0f;
  bf16x4 pw = *(const bf16x4*)&PW[(size_t)b * RW + r4];

  for (int s = 0; s < NS; ++s) {
    const uint32_t tv = (uint32_t)s;
    const int par = s & 1;

    // prefetch next-step PW (in flight during poll spin)
    int sn = (s + 1 < NS) ? (s + 1) : (NS - 1);
    bf16x4 pwn = *(const bf16x4*)&PW[(size_t)(sn * NB + b) * RW + r4];

    // ---- wave-coalesced flag poll: 1 dwordx4/lane/round, sc1 (device scope) ----
    {
      const uint32_t* fp = par ? fB : fA;
      int tries = 0;
      for (;;) {
        u32x4 f;
        asm volatile("global_load_dwordx4 %0, %1, off sc1\n\t"
                     "s_waitcnt vmcnt(0)"
                     : "=v"(f) : "v"(fp));
        bool ok = (f[0] == tv) & (f[1] == tv) & (f[2] == tv) & (f[3] == tv);
        if (__ballot(ok) == ~0ull) break;
        if (++tries > 768) {   // liveness net: agent-atomic re-check
          uint32_t g0 = __hip_atomic_load(fp + 0, __ATOMIC_RELAXED, __HIP_MEMORY_SCOPE_AGENT);
          uint32_t g1 = __hip_atomic_load(fp + 1, __ATOMIC_RELAXED, __HIP_MEMORY_SCOPE_AGENT);
          uint32_t g2 = __hip_atomic_load(fp + 2, __ATOMIC_RELAXED, __HIP_MEMORY_SCOPE_AGENT);
          uint32_t g3 = __hip_atomic_load(fp + 3, __ATOMIC_RELAXED, __HIP_MEMORY_SCOPE_AGENT);
          bool ok2 = (g0 == tv) & (g1 == tv) & (g2 == tv) & (g3 == tv);
          if (__ballot(ok2) == ~0ull) break;
          tries = 0;
        }
        __builtin_amdgcn_s_sleep(1);
      }
    }

    // ---- one-shot dense data load: per wave-instr 4x256B contiguous chunks ----
    const short* sp = par ? dB : dA;
    bf16x8 d0, d1, d2, d3;
    asm volatile("global_load_dwordx4 %0, %4, off sc1\n\t"
                 "global_load_dwordx4 %1, %4, off offset:256 sc1\n\t"
                 "global_load_dwordx4 %2, %4, off offset:512 sc1\n\t"
                 "global_load_dwordx4 %3, %4, off offset:768 sc1\n\t"
                 "s_waitcnt vmcnt(0)"
                 : "=v"(d0), "=v"(d1), "=v"(d2), "=v"(d3) : "v"(sp));

    short* buf = &h_lds[par][0];
    short* dst = buf + db * 520 + dlo;
    *(bf16x8*)&dst[0]   = d0;
    *(bf16x8*)&dst[128] = d1;
    *(bf16x8*)&dst[256] = d2;
    *(bf16x8*)&dst[384] = d3;
    __syncthreads();

    // ---- gates = PW + Whh @ h : 16 MFMAs in four independent dep-chains ----
    f32x4 acc0, acc1, acc2, acc3;
    #pragma unroll
    for (int q = 0; q < 4; ++q) {
      acc0[q] = bf2f(pw[q]); acc1[q] = 0.0f; acc2[q] = 0.0f; acc3[q] = 0.0f;
    }
    #pragma unroll
    for (int kc = 0; kc < 16; kc += 4) {
      bf16x8 h0 = *(bf16x8*)((const char*)buf + b * 1040 + (kc + 0) * 64 + hi * 16);
      bf16x8 h1 = *(bf16x8*)((const char*)buf + b * 1040 + (kc + 1) * 64 + hi * 16);
      bf16x8 h2 = *(bf16x8*)((const char*)buf + b * 1040 + (kc + 2) * 64 + hi * 16);
      bf16x8 h3 = *(bf16x8*)((const char*)buf + b * 1040 + (kc + 3) * 64 + hi * 16);
      acc0 = MFMA16(a[kc + 0], h0, acc0);
      acc1 = MFMA16(a[kc + 1], h1, acc1);
      acc2 = MFMA16(a[kc + 2], h2, acc2);
      acc3 = MFMA16(a[kc + 3], h3, acc3);
    }
    f32x4 acc;
    #pragma unroll
    for (int q = 0; q < 4; ++q) acc[q] = (acc0[q] + acc1[q]) + (acc2[q] + acc3[q]);

    // ---- cell (1 j per lane) ----
    float c = sigf(acc[1]) * cst + sigf(acc[0]) * tanh_f(acc[2]);
    cst = c;
    short hv = f2bf(sigf(acc[3]) * tanh_f(c));

    // ---- publish h(s+1): pair-pack via shfl_xor(16); sc1 dword stores ----
    unsigned int own = (unsigned int)(unsigned short)hv;
    unsigned int part = (unsigned int)__shfl_xor((int)own, 16);
    const int npar = (s + 1) & 1;
    if ((hi & 1) == 0) {
      unsigned int val = own | (part << 16);          // mem: [jl]=own, [jl+1]=part
      short* hp = hdat + (npar << 14) + b * 512 + jl;
      asm volatile("global_store_dword %0, %1, off sc1" :: "v"(hp), "v"(val) : "memory");
    }
    asm volatile("s_waitcnt vmcnt(0)" ::: "memory");  // sc1 stores ack'd at coherence point
    if (lane == 0) {                                  // per-wave flag, no trailing barrier
      uint32_t* fq = flags + npar * 256 + bk * 8 + wv;
      asm volatile("global_store_dword %0, %1, off sc1"
                   :: "v"(fq), "v"((uint32_t)(s + 1)) : "memory");
    }
    word_hs[((size_t)b * NS + s) * NH + jl] = hv;     // off the critical path
    pw = pwn;
  }
}

// ===================== tag projection + log_softmax =====================
// M=64 tags (padded), N=128 words/block, K=512. Wt staged bf16 in LDS (two K-halves).
__global__ __launch_bounds__(256) void k_tags(
    const short* __restrict__ word_hs, const float* __restrict__ Wt,
    const float* __restrict__ bt, float* __restrict__ out)
{
  __shared__ __align__(16) short Ws[64 * 256];   // 32KB: one K-half
  const int tid = threadIdx.x, lane = tid & 63, wid = tid >> 6;
  const int lo = lane & 15, hi = lane >> 4;
  const int n0 = blockIdx.x * 128;
  const int wb = n0 + wid * 32;

  f32x4 acc[4][2];
  #pragma unroll
  for (int fm = 0; fm < 4; ++fm)
    #pragma unroll
    for (int fn = 0; fn < 2; ++fn) acc[fm][fn] = (f32x4)0.0f;

  for (int half = 0; half < 2; ++half) {
    __syncthreads();
    for (int cid = tid; cid < 2048; cid += 256) {   // 64 rows x 32 chunks
      int row = cid >> 5, cp = cid & 31;
      int kch = cp ^ (row & 7);
      bf16x8 v;
      if (row < NT) {
        const float* src = &Wt[(size_t)row * KW + half * 256 + kch * 8];
        #pragma unroll
        for (int e = 0; e < 8; ++e) v[e] = f2bf(src[e]);
      } else v = (bf16x8)0;
      *(bf16x8*)&Ws[row * 256 + cp * 8] = v;
    }
    __syncthreads();
    #pragma unroll
    for (int kc = 0; kc < 8; ++kc) {
      bf16x8 bfr[2];
      #pragma unroll
      for (int fn = 0; fn < 2; ++fn) {
        int w = wb + fn * 16 + lo;
        bfr[fn] = *(const bf16x8*)&word_hs[(size_t)w * KW + half * 256 + kc * 32 + hi * 8];
      }
      #pragma unroll
      for (int fm = 0; fm < 4; ++fm) {
        int row = fm * 16 + lo;
        int ch = (kc * 4 + hi) ^ (row & 7);
        bf16x8 av = *(bf16x8*)&Ws[row * 256 + ch * 8];
        acc[fm][0] = MFMA16(av, bfr[0], acc[fm][0]);
        acc[fm][1] = MFMA16(av, bfr[1], acc[fm][1]);
      }
    }
  }

  #pragma unroll
  for (int fn = 0; fn < 2; ++fn) {
    int w = wb + fn * 16 + lo;
    float lg[16];
    float m = -1e30f;
    #pragma unroll
    for (int fm = 0; fm < 4; ++fm)
      #pragma unroll
      for (int q = 0; q < 4; ++q) {
        int tg = fm * 16 + hi * 4 + q;
        float bv = (tg < NT) ? bt[tg] : 0.0f;
        float v = acc[fm][fn][q] + bv;
        lg[fm * 4 + q] = v;
        if (tg < NT) m = fmaxf(m, v);
      }
    m = fmaxf(m, __shfl_xor(m, 16));
    m = fmaxf(m, __shfl_xor(m, 32));
    float s = 0.0f;
    #pragma unroll
    for (int fm = 0; fm < 4; ++fm)
      #pragma unroll
      for (int q = 0; q < 4; ++q) {
        int tg = fm * 16 + hi * 4 + q;
        if (tg < NT) s += __expf(lg[fm * 4 + q] - m);
      }
    s += __shfl_xor(s, 16);
    s += __shfl_xor(s, 32);
    float lz = m + __logf(s);
    #pragma unroll
    for (int fm = 0; fm < 4; ++fm)
      #pragma unroll
      for (int q = 0; q < 4; ++q) {
        int tg = fm * 16 + hi * 4 + q;
        if (tg < NT) out[(size_t)w * NT + tg] = lg[fm * 4 + q] - lz;
      }
  }
}

// ===================== launch =====================
extern "C" void kernel_launch(void* const* d_in, const int* in_sizes, int n_in,
                              void* d_out, int out_size, void* d_ws, size_t ws_size,
                              hipStream_t stream) {
  const int*   char_idx = (const int*)  d_in[0];
  const int*   word_idx = (const int*)  d_in[1];
  const float* char_emb = (const float*)d_in[2];
  const float* word_emb = (const float*)d_in[3];
  const float* Wc_ih    = (const float*)d_in[4];
  const float* Wc_hh    = (const float*)d_in[5];
  const float* bc       = (const float*)d_in[6];
  const float* Ww_ih    = (const float*)d_in[7];
  const float* Ww_hh    = (const float*)d_in[8];
  const float* bw       = (const float*)d_in[9];
  const float* Wt       = (const float*)d_in[10];
  const float* bt       = (const float*)d_in[11];
  float* out = (float*)d_out;

  const size_t MB = 1ull << 20;
  uint8_t* w8 = (uint8_t*)d_ws;
  float* PEb   = (float*)(w8 + 0);                 // 512K
  short* WhhC  = (short*)(w8 + 512 * 1024);        // 512K
  short* WihW  = (short*)(w8 + 1 * MB);            // 2M
  short* WhhW  = (short*)(w8 + 3 * MB);            // 2M
  float* bwI   = (float*)(w8 + 5 * MB);            // 8K
  uint8_t* xb  = (uint8_t*)(w8 + 5 * MB + 64 * 1024);  // 64K hdat + 2K flags
  short* hA    = (short*)(w8 + 6 * MB);            // 16M
  short* hB    = (short*)(w8 + 22 * MB);           // 16M
  short* whs   = (short*)(w8 + 6 * MB);            // 32M (reuses hA/hB after k_xw)
  float* cC    = (float*)(w8 + 38 * MB);           // 32M
  short* Xw    = (short*)(w8 + 38 * MB);           // 32M (reuses cC after char steps)
  short* PW    = (short*)(w8 + 70 * MB);           // 128M

  k_prep_pe<<<128, 256, 0, stream>>>(char_emb, Wc_ih, bc, PEb);
  k_prep_w<<<2048, 256, 0, stream>>>(Wc_hh, Ww_ih, Ww_hh, bw, WhhC, WihW, WhhW, bwI);

  // char LSTM
  k_char0<<<NWRD, 256, 0, stream>>>(char_idx, PEb, cC, hA);
  for (int t = 1; t < NC; ++t) {
    short* src = (t & 1) ? hA : hB;
    short* dst = (t & 1) ? hB : hA;
    gemm_epi<256, 0><<<dim3(256, 8), 256, 0, stream>>>(
        WhhC, src, PEb, char_idx, t, cC, dst, nullptr, nullptr);
  }
  // h_12 ends in hB

  // word LSTM input projections for all timesteps
  k_xw<<<NWRD, 64, 0, stream>>>(word_idx, word_emb, hB, Xw);
  gemm_epi<512, 1><<<dim3(256, 16), 256, 0, stream>>>(
      WihW, Xw, nullptr, nullptr, 0, nullptr, nullptr, bwI, PW);

  // persistent recurrence: zero h slot0 (h_{-1}=0) + both flag slots
  hipMemsetAsync(xb, 0, 64 * 1024 + 2048, stream);
  k_word<<<32, 512, 0, stream>>>(WhhW, PW, xb, whs);

  // tags + log_softmax
  k_tags<<<256, 256, 0, stream>>>(whs, Wt, bt, out);
}